// Round 11
// baseline (769.231 us; speedup 1.0000x reference)
//
#include <hip/hip_runtime.h>
#include <cstdint>
#include <cstddef>

#define L_SEQ 4096
#define BATCH 32
#define DIN 128
#define DLAT 512
#define CHUNK 32
#define NCHUNK (L_SEQ / CHUNK)   // 128
#define MC 4                     // chunks per block in kernel A
#define NCH 8                    // channels per thread in kernel A

__device__ __forceinline__ void async_copy16(const float* g, float* l) {
    __builtin_amdgcn_global_load_lds(
        (const __attribute__((address_space(1))) unsigned int*)g,
        (__attribute__((address_space(3))) unsigned int*)l,
        16, 0, 0);
}

// Quad-perm DPP cross-lane adds (lanes tid&3 form a DPP quad). Pure VALU.
__device__ __forceinline__ float dpp_add_xor1(float x) {
    int r = __builtin_amdgcn_update_dpp(0, __builtin_bit_cast(int, x),
                                        0xB1, 0xF, 0xF, true);
    return x + __builtin_bit_cast(float, r);
}
__device__ __forceinline__ float dpp_add_xor2(float x) {
    int r = __builtin_amdgcn_update_dpp(0, __builtin_bit_cast(int, x),
                                        0x4E, 0xF, 0xF, true);
    return x + __builtin_bit_cast(float, r);
}

// ---------------------------------------------------------------------------
// Kernel A: fused GEMM + chunk-local scan. NCH=8 channels/thread (all 512
// channels in one block), MC=4 chunks/block, double-buffered LDS.
// Rationale: per thread-q, 8 ds_read_b128 now feed 256 FMAs -> shared LDS
// pipe ~62% subscribed (was 124% at NCH=4, which capped VALUBusy ~61%).
// Costs ~300 VGPR -> 1 block/CU; latency self-hidden by the 600+cy
// independent FMA window between LDS loads. grid (NCHUNK/MC, BATCH, 1).
// ---------------------------------------------------------------------------
__global__ __launch_bounds__(256, 1) void rnn_local(
    const float* __restrict__ X,   // [L, B, DIN]
    const float* __restrict__ wx,  // [DIN, DLAT]
    const float* __restrict__ wh,  // [DLAT]
    const float* __restrict__ bh,  // [DLAT]
    float* __restrict__ out,       // [L, B, DLAT]  (scratch: pre-tanh locals)
    float* __restrict__ F)         // [NCHUNK, B, DLAT] chunk-final locals
{
    __shared__ float Xs[2][CHUNK * DIN];  // 2 x 16 KiB, double buffer

    const int tid = threadIdx.x;
    const int c0 = blockIdx.x * MC;    // first chunk of this block
    const int b  = blockIdx.y;         // batch
    const int ch = tid >> 2;           // 0..63
    const int r  = tid & 3;            // K-slice 0..3

    // Staging: shot s stages timesteps 8s..8s+7 of chunk c.
    // ts = tid>>5 (0..7), k = (tid&31)*4. LDS float idx = s*1024 + tid*4
    // == (8s+ts)*128 + k  -> Xs[buf][t*128+k], linear in tid per shot.
    const int ts  = tid >> 5;
    const int k16 = (tid & 31) * 4;
    const float* gbase = X + ((size_t)ts * BATCH + b) * DIN + k16;

#define STAGE(cc, buf)                                                          \
    {                                                                           \
        const float* g0 = gbase + (size_t)(cc) * CHUNK * BATCH * DIN;           \
        float* l0 = &Xs[buf][0] + tid * 4;                                      \
        _Pragma("unroll")                                                       \
        for (int s = 0; s < 4; ++s)                                             \
            async_copy16(g0 + (size_t)s * 8 * BATCH * DIN, l0 + s * 1024);      \
    }

    // Prologue: stage first chunk into buffer 0, load weights meanwhile.
    STAGE(c0, 0)

    // wx slices for 8 channels: k = 8*r + 32*s + i ; j_n = n*64 + ch
    float wxr[NCH][32];
    float whn[NCH], bh4[NCH];
#pragma unroll
    for (int n = 0; n < NCH; ++n) {
        whn[n] = wh[n * 64 + ch];
        bh4[n] = bh[n * 64 + ch] * 0.25f;   // exact scale; 4 lanes sum to +bh
    }
#pragma unroll
    for (int s = 0; s < 4; ++s)
#pragma unroll
        for (int i = 0; i < 8; ++i) {
            const size_t krow = (size_t)(8 * r + 32 * s + i) * DLAT;
#pragma unroll
            for (int n = 0; n < NCH; ++n)
                wxr[n][s * 8 + i] = wx[krow + n * 64 + ch];
        }

    asm volatile("s_waitcnt vmcnt(0)" ::: "memory");
    __syncthreads();

    for (int m = 0; m < MC; ++m) {
        const int c   = c0 + m;
        const int buf = m & 1;
        if (m + 1 < MC)
            STAGE(c + 1, (m + 1) & 1)   // async into other buffer during compute

        float l[NCH];
#pragma unroll
        for (int n = 0; n < NCH; ++n) l[n] = 0.f;

        for (int g = 0; g < 8; ++g) {
            float snap[NCH];
#pragma unroll
            for (int n = 0; n < NCH; ++n) snap[n] = 0.f;
#pragma unroll
            for (int q = 0; q < 4; ++q) {
                const float* xt = &Xs[buf][0] + (g * 4 + q) * DIN + 8 * r;
                float acc[NCH];
#pragma unroll
                for (int n = 0; n < NCH; ++n) acc[n] = bh4[n];
#pragma unroll
                for (int s = 0; s < 4; ++s) {
                    const float4 xa = *(const float4*)(xt + 32 * s);
                    const float4 xc = *(const float4*)(xt + 32 * s + 4);
#pragma unroll
                    for (int n = 0; n < NCH; ++n) {
                        acc[n] = fmaf(xa.x, wxr[n][s * 8 + 0], acc[n]);
                        acc[n] = fmaf(xa.y, wxr[n][s * 8 + 1], acc[n]);
                        acc[n] = fmaf(xa.z, wxr[n][s * 8 + 2], acc[n]);
                        acc[n] = fmaf(xa.w, wxr[n][s * 8 + 3], acc[n]);
                        acc[n] = fmaf(xc.x, wxr[n][s * 8 + 4], acc[n]);
                        acc[n] = fmaf(xc.y, wxr[n][s * 8 + 5], acc[n]);
                        acc[n] = fmaf(xc.z, wxr[n][s * 8 + 6], acc[n]);
                        acc[n] = fmaf(xc.w, wxr[n][s * 8 + 7], acc[n]);
                    }
                }
#pragma unroll
                for (int n = 0; n < NCH; ++n) {
                    float a = dpp_add_xor1(acc[n]);
                    a = dpp_add_xor2(a);
                    l[n] = fmaf(l[n], whn[n], a);   // a already includes bh
                    snap[n] = (q == r) ? l[n] : snap[n];
                }
            }
            const int t = c * CHUNK + g * 4 + r;
            const size_t row = (size_t)t * (BATCH * DLAT) + (size_t)b * DLAT + ch;
#pragma unroll
            for (int n = 0; n < NCH; ++n)
                out[row + n * 64] = snap[n];
        }

        if (r == 0) {
            const size_t fb = ((size_t)c * BATCH + b) * DLAT + ch;
#pragma unroll
            for (int n = 0; n < NCH; ++n)
                F[fb + n * 64] = l[n];
        }

        asm volatile("s_waitcnt vmcnt(0)" ::: "memory");
        __syncthreads();
    }
#undef STAGE
}

// ---------------------------------------------------------------------------
// Kernel B0: sequential prefix over chunks -> Hpre[c] = state entering chunk c.
// grid (BATCH), block 128 (thread owns float4 of channels). Tiny.
// ---------------------------------------------------------------------------
__global__ __launch_bounds__(128) void rnn_prefix(
    const float* __restrict__ h0,   // [B, DLAT]
    const float* __restrict__ wh,   // [DLAT]
    const float* __restrict__ F,    // [NCHUNK, B, DLAT]
    float* __restrict__ Hpre)       // [NCHUNK, B, DLAT]
{
    const int b  = blockIdx.x;
    const int j4 = threadIdx.x * 4;
    const size_t cb = (size_t)b * DLAT + j4;

    float4 w4 = *(const float4*)(wh + j4);
    float wv[4] = {w4.x, w4.y, w4.z, w4.w};
    float wc[4];
#pragma unroll
    for (int k = 0; k < 4; ++k) {
        float t = wv[k];
        t = t * t; t = t * t; t = t * t; t = t * t; t = t * t;  // wh^32 (>0)
        wc[k] = t;
    }

    float4 h4 = *(const float4*)(h0 + cb);
    float Hv[4] = {h4.x, h4.y, h4.z, h4.w};

    for (int cg = 0; cg < NCHUNK / 4; ++cg) {
        float4 Fv[4];
#pragma unroll
        for (int i = 0; i < 4; ++i)
            Fv[i] = *(const float4*)(F + (size_t)(cg * 4 + i) * (BATCH * DLAT) + cb);
#pragma unroll
        for (int i = 0; i < 4; ++i) {
            float4 o = {Hv[0], Hv[1], Hv[2], Hv[3]};
            *(float4*)(Hpre + (size_t)(cg * 4 + i) * (BATCH * DLAT) + cb) = o;
            Hv[0] = fmaf(Hv[0], wc[0], Fv[i].x);
            Hv[1] = fmaf(Hv[1], wc[1], Fv[i].y);
            Hv[2] = fmaf(Hv[2], wc[2], Fv[i].z);
            Hv[3] = fmaf(Hv[3], wc[3], Fv[i].w);
        }
    }
}

// ---------------------------------------------------------------------------
// Kernel C: pure streaming fixup: out_t = tanh(l_t + wh^{d+1} * Hpre[c]).
// grid (NCHUNK/2, BATCH), block 256 = 2 chunks x 128 threads x float4.
// ---------------------------------------------------------------------------
__global__ __launch_bounds__(256) void rnn_fix2(
    const float* __restrict__ wh,    // [DLAT]
    const float* __restrict__ Hpre,  // [NCHUNK, B, DLAT]
    float* __restrict__ out)         // [L, B, DLAT] in-place
{
    const int tid = threadIdx.x;
    const int c   = blockIdx.x * 2 + (tid >> 7);
    const int b   = blockIdx.y;
    const int j4  = (tid & 127) * 4;
    const size_t cb = (size_t)b * DLAT + j4;

    float4 w4 = *(const float4*)(wh + j4);
    float4 H4 = *(const float4*)(Hpre + (size_t)c * (BATCH * DLAT) + cb);
    float wv[4] = {w4.x, w4.y, w4.z, w4.w};
    float Hv[4] = {H4.x, H4.y, H4.z, H4.w};

    float sc[4] = {wv[0], wv[1], wv[2], wv[3]};
#pragma unroll 4
    for (int d = 0; d < CHUNK; ++d) {
        const size_t off = ((size_t)(c * CHUNK + d) * BATCH + b) * DLAT + j4;
        float4 l4 = *(const float4*)(out + off);
        float4 res;
        res.x = tanhf(fmaf(sc[0], Hv[0], l4.x));
        res.y = tanhf(fmaf(sc[1], Hv[1], l4.y));
        res.z = tanhf(fmaf(sc[2], Hv[2], l4.z));
        res.w = tanhf(fmaf(sc[3], Hv[3], l4.w));
        *(float4*)(out + off) = res;
        sc[0] *= wv[0]; sc[1] *= wv[1]; sc[2] *= wv[2]; sc[3] *= wv[3];
    }
}

// Fallback (ws too small for Hpre): fold H per block from F, as in round 6.
__global__ __launch_bounds__(256) void rnn_fix(
    const float* __restrict__ h0, const float* __restrict__ wh,
    const float* __restrict__ F, float* __restrict__ out)
{
    const int tid = threadIdx.x;
    const int c   = blockIdx.x * 2 + (tid >> 7);
    const int b   = blockIdx.y;
    const int j4  = (tid & 127) * 4;
    const size_t cb = (size_t)b * DLAT + j4;

    float4 h4 = *(const float4*)(h0 + cb);
    float4 w4 = *(const float4*)(wh + j4);
    float Hv[4] = {h4.x, h4.y, h4.z, h4.w};
    float wv[4] = {w4.x, w4.y, w4.z, w4.w};
    float wc[4];
#pragma unroll
    for (int k = 0; k < 4; ++k) {
        float t = wv[k];
        t = t * t; t = t * t; t = t * t; t = t * t; t = t * t;
        wc[k] = t;
    }
    for (int cc = 0; cc < c; ++cc) {
        const float4 Fv = *(const float4*)(F + ((size_t)cc * BATCH + b) * DLAT + j4);
        Hv[0] = fmaf(Hv[0], wc[0], Fv.x);
        Hv[1] = fmaf(Hv[1], wc[1], Fv.y);
        Hv[2] = fmaf(Hv[2], wc[2], Fv.z);
        Hv[3] = fmaf(Hv[3], wc[3], Fv.w);
    }
    float sc[4] = {wv[0], wv[1], wv[2], wv[3]};
    for (int d = 0; d < CHUNK; ++d) {
        const size_t off = ((size_t)(c * CHUNK + d) * BATCH + b) * DLAT + j4;
        float4 l4 = *(const float4*)(out + off);
        float4 res;
        res.x = tanhf(fmaf(sc[0], Hv[0], l4.x));
        res.y = tanhf(fmaf(sc[1], Hv[1], l4.y));
        res.z = tanhf(fmaf(sc[2], Hv[2], l4.z));
        res.w = tanhf(fmaf(sc[3], Hv[3], l4.w));
        *(float4*)(out + off) = res;
        sc[0] *= wv[0]; sc[1] *= wv[1]; sc[2] *= wv[2]; sc[3] *= wv[3];
    }
}

extern "C" void kernel_launch(void* const* d_in, const int* in_sizes, int n_in,
                              void* d_out, int out_size, void* d_ws, size_t ws_size,
                              hipStream_t stream) {
    const float* X  = (const float*)d_in[0];
    const float* h0 = (const float*)d_in[1];
    const float* wx = (const float*)d_in[2];
    const float* wh = (const float*)d_in[3];
    const float* bh = (const float*)d_in[4];
    float* out = (float*)d_out;

    const size_t seg = (size_t)NCHUNK * BATCH * DLAT;  // 2M floats = 8 MiB
    float* F    = (float*)d_ws;
    float* Hpre = F + seg;

    rnn_local<<<dim3(NCHUNK / MC, BATCH, 1), dim3(256), 0, stream>>>(X, wx, wh, bh, out, F);
    if (ws_size >= 2 * seg * sizeof(float)) {
        rnn_prefix<<<dim3(BATCH), dim3(128), 0, stream>>>(h0, wh, F, Hpre);
        rnn_fix2<<<dim3(NCHUNK / 2, BATCH), dim3(256), 0, stream>>>(wh, Hpre, out);
    } else {
        rnn_fix<<<dim3(NCHUNK / 2, BATCH), dim3(256), 0, stream>>>(h0, wh, F, out);
    }
}

// Round 13
// 238.175 us; speedup vs baseline: 3.2297x; 3.2297x over previous
//
#include <hip/hip_runtime.h>
#include <cstdint>
#include <cstddef>

#define L_SEQ 4096
#define BATCH 32
#define DIN 128
#define DLAT 512
#define CHUNK 32
#define NCHUNK (L_SEQ / CHUNK)   // 128

typedef __attribute__((ext_vector_type(8))) short short8;
typedef __attribute__((ext_vector_type(4))) float f32x4;

// 3-way Dekker-style split: x = h + m + l + r, |r| <= 2^-27 |x|.
// Each subtraction is fp32-exact (standard split property).
__device__ __forceinline__ unsigned short bf16rne(float x) {
    unsigned int b = __builtin_bit_cast(unsigned int, x);
    unsigned int r = b + 0x7FFFu + ((b >> 16) & 1u);
    return (unsigned short)(r >> 16);
}
__device__ __forceinline__ float bf16tof(unsigned short h) {
    return __builtin_bit_cast(float, (unsigned int)h << 16);
}
__device__ __forceinline__ void bf16split3(float x, unsigned short& h,
                                           unsigned short& m, unsigned short& l) {
    h = bf16rne(x);
    float r1 = x - bf16tof(h);
    m = bf16rne(r1);
    float r2 = r1 - bf16tof(m);
    l = bf16rne(r2);
}

__device__ __forceinline__ void async_copy16(const float* g, float* l) {
    __builtin_amdgcn_global_load_lds(
        (const __attribute__((address_space(1))) unsigned int*)g,
        (__attribute__((address_space(3))) unsigned int*)l,
        16, 0, 0);
}
__device__ __forceinline__ float dpp_add_xor1(float x) {
    int r = __builtin_amdgcn_update_dpp(0, __builtin_bit_cast(int, x),
                                        0xB1, 0xF, 0xF, true);
    return x + __builtin_bit_cast(float, r);
}
__device__ __forceinline__ float dpp_add_xor2(float x) {
    int r = __builtin_amdgcn_update_dpp(0, __builtin_bit_cast(int, x),
                                        0x4E, 0xF, 0xF, true);
    return x + __builtin_bit_cast(float, r);
}

// ---------------------------------------------------------------------------
// Kernel W: one-time transform of wx [128][512] fp32 into MFMA B-fragment
// layout, bf16 h/m/l. Frag fid = kt*32 + nt; lane holds col n = nt*16+(lane&15),
// k = kt*32 + (lane>>4)*8 + i. 3 x 128 KB into ws.
// ---------------------------------------------------------------------------
__global__ __launch_bounds__(256) void wx_transform(
    const float* __restrict__ wx,
    unsigned short* __restrict__ wxtH,
    unsigned short* __restrict__ wxtM,
    unsigned short* __restrict__ wxtL)
{
    const int gid  = blockIdx.x * 256 + threadIdx.x;  // 8192 threads
    const int fid  = gid >> 6;        // 0..127
    const int lane = gid & 63;
    const int kt = fid >> 5, nt = fid & 31;
    const int n  = nt * 16 + (lane & 15);
    const int kb = kt * 32 + (lane >> 4) * 8;

    short8 h8, m8, l8;
#pragma unroll
    for (int i = 0; i < 8; ++i) {
        unsigned short h, m, l;
        bf16split3(wx[(size_t)(kb + i) * DLAT + n], h, m, l);
        h8[i] = (short)h; m8[i] = (short)m; l8[i] = (short)l;
    }
    ((short8*)wxtH)[fid * 64 + lane] = h8;
    ((short8*)wxtM)[fid * 64 + lane] = m8;
    ((short8*)wxtL)[fid * 64 + lane] = l8;
}

// ---------------------------------------------------------------------------
// Kernel A (MFMA): per block = chunk c x batch b x ALL 512 channels.
// Phase S: X chunk -> regs -> bf16 h/m/l -> LDS A-frags.
// Phase M: 6-product emulation (hh, hm, mh, hl, lh, mm; residual 2^-27),
// 384 MFMAs/wave, accumulated smallest-first into fp32 acc.
// Phase U/scan: acc -> LDS U[16][520] -> serial scan (2 ch/thread) -> out, F.
// grid (NCHUNK, BATCH) = 4096 blocks, 256 threads.
// ---------------------------------------------------------------------------
__global__ __launch_bounds__(256) void rnn_local_mfma(
    const float* __restrict__ X,          // [L, B, DIN]
    const unsigned short* __restrict__ wxtH,
    const unsigned short* __restrict__ wxtM,
    const unsigned short* __restrict__ wxtL,
    const float* __restrict__ wh,         // [DLAT]
    const float* __restrict__ bh,         // [DLAT]
    float* __restrict__ out,              // [L, B, DLAT] pre-tanh locals
    float* __restrict__ F)                // [NCHUNK, B, DLAT]
{
    __shared__ unsigned short AF[24 * 512];  // 8 frags x 3 parts x 64 lanes x 8 = 24 KB
    __shared__ float U[16 * 520];            // 33,280 B (pad 520 -> 2-way max)

    const int tid  = threadIdx.x;
    const int c = blockIdx.x, b = blockIdx.y;
    const int w = tid >> 6, lane = tid & 63;

    // ---- Phase S: stage + 3-way convert. 2 frag-slots per thread. ----
#pragma unroll
    for (int sl = 0; sl < 2; ++sl) {
        const int slot = tid + sl * 256;
        const int f  = slot >> 6;        // m*4 + kt  (0..7)
        const int ls = slot & 63;
        const int m  = f >> 2, kt = f & 3;
        const int t  = c * CHUNK + m * 16 + (ls & 15);
        const int kb = kt * 32 + (ls >> 4) * 8;
        const float* p = X + ((size_t)t * BATCH + b) * DIN + kb;
        const float4 va = *(const float4*)p;
        const float4 vb = *(const float4*)(p + 4);
        float v[8] = {va.x, va.y, va.z, va.w, vb.x, vb.y, vb.z, vb.w};
        short8 h8, m8, l8;
#pragma unroll
        for (int i = 0; i < 8; ++i) {
            unsigned short h, mm, l;
            bf16split3(v[i], h, mm, l);
            h8[i] = (short)h; m8[i] = (short)mm; l8[i] = (short)l;
        }
        ((short8*)AF)[(f * 3 + 0) * 64 + ls] = h8;
        ((short8*)AF)[(f * 3 + 1) * 64 + ls] = m8;
        ((short8*)AF)[(f * 3 + 2) * 64 + ls] = l8;
    }
    __syncthreads();

    // ---- Phase M: MFMA. Wave w owns channels [w*128, w*128+128). ----
    f32x4 acc[2][8];
#pragma unroll
    for (int m = 0; m < 2; ++m)
#pragma unroll
        for (int j = 0; j < 8; ++j)
            acc[m][j] = (f32x4){0.f, 0.f, 0.f, 0.f};

    const short8* AFv = (const short8*)AF;
    const short8* BH  = (const short8*)wxtH;
    const short8* BM  = (const short8*)wxtM;
    const short8* BL  = (const short8*)wxtL;

#pragma unroll
    for (int kt = 0; kt < 4; ++kt) {
        const short8 a0h = AFv[((0 * 4 + kt) * 3 + 0) * 64 + lane];
        const short8 a0m = AFv[((0 * 4 + kt) * 3 + 1) * 64 + lane];
        const short8 a0l = AFv[((0 * 4 + kt) * 3 + 2) * 64 + lane];
        const short8 a1h = AFv[((1 * 4 + kt) * 3 + 0) * 64 + lane];
        const short8 a1m = AFv[((1 * 4 + kt) * 3 + 1) * 64 + lane];
        const short8 a1l = AFv[((1 * 4 + kt) * 3 + 2) * 64 + lane];
#pragma unroll
        for (int j = 0; j < 8; ++j) {
            const int idx = (kt * 32 + w * 8 + j) * 64 + lane;
            const short8 bh8 = BH[idx];
            const short8 bm8 = BM[idx];
            const short8 bl8 = BL[idx];
            // smallest-first: mm, al*bh, ah*bl, am*bh, ah*bm, ah*bh
            acc[0][j] = __builtin_amdgcn_mfma_f32_16x16x32_bf16(a0m, bm8, acc[0][j], 0, 0, 0);
            acc[0][j] = __builtin_amdgcn_mfma_f32_16x16x32_bf16(a0l, bh8, acc[0][j], 0, 0, 0);
            acc[0][j] = __builtin_amdgcn_mfma_f32_16x16x32_bf16(a0h, bl8, acc[0][j], 0, 0, 0);
            acc[0][j] = __builtin_amdgcn_mfma_f32_16x16x32_bf16(a0m, bh8, acc[0][j], 0, 0, 0);
            acc[0][j] = __builtin_amdgcn_mfma_f32_16x16x32_bf16(a0h, bm8, acc[0][j], 0, 0, 0);
            acc[0][j] = __builtin_amdgcn_mfma_f32_16x16x32_bf16(a0h, bh8, acc[0][j], 0, 0, 0);
            acc[1][j] = __builtin_amdgcn_mfma_f32_16x16x32_bf16(a1m, bm8, acc[1][j], 0, 0, 0);
            acc[1][j] = __builtin_amdgcn_mfma_f32_16x16x32_bf16(a1l, bh8, acc[1][j], 0, 0, 0);
            acc[1][j] = __builtin_amdgcn_mfma_f32_16x16x32_bf16(a1h, bl8, acc[1][j], 0, 0, 0);
            acc[1][j] = __builtin_amdgcn_mfma_f32_16x16x32_bf16(a1m, bh8, acc[1][j], 0, 0, 0);
            acc[1][j] = __builtin_amdgcn_mfma_f32_16x16x32_bf16(a1h, bm8, acc[1][j], 0, 0, 0);
            acc[1][j] = __builtin_amdgcn_mfma_f32_16x16x32_bf16(a1h, bh8, acc[1][j], 0, 0, 0);
        }
    }

    // ---- Phase U/scan: two m-tiles through one U buffer. ----
    const int ch = tid * 2;                           // 2 channels per thread
    const float2 whv = *(const float2*)(wh + ch);
    const float2 bhv = *(const float2*)(bh + ch);
    float l0 = 0.f, l1 = 0.f;

#pragma unroll
    for (int m = 0; m < 2; ++m) {
        // D layout (m89-verified): col = lane&15, row = (lane>>4)*4 + reg.
#pragma unroll
        for (int j = 0; j < 8; ++j) {
            const int col = w * 128 + j * 16 + (lane & 15);
#pragma unroll
            for (int r4 = 0; r4 < 4; ++r4)
                U[((lane >> 4) * 4 + r4) * 520 + col] = acc[m][j][r4];
        }
        __syncthreads();
        for (int tl = 0; tl < 16; ++tl) {
            const float2 u = *(const float2*)&U[tl * 520 + ch];
            l0 = fmaf(l0, whv.x, u.x + bhv.x);
            l1 = fmaf(l1, whv.y, u.y + bhv.y);
            const int t = c * CHUNK + m * 16 + tl;
            float2 o; o.x = l0; o.y = l1;
            *(float2*)(out + ((size_t)t * BATCH + b) * DLAT + ch) = o;
        }
        __syncthreads();   // scan done before U overwritten / before exit
    }

    float2 fo; fo.x = l0; fo.y = l1;
    *(float2*)(F + ((size_t)c * BATCH + b) * DLAT + ch) = fo;
}

// ---------------------------------------------------------------------------
// VALU fallback kernel A (proven R8 config) — used only if ws too small.
// ---------------------------------------------------------------------------
#define VMC 4
#define VNCH 4
__global__ __launch_bounds__(256, 2) void rnn_local_valu(
    const float* __restrict__ X, const float* __restrict__ wx,
    const float* __restrict__ wh, const float* __restrict__ bh,
    float* __restrict__ out, float* __restrict__ F)
{
    __shared__ float Xs[2][CHUNK * DIN];
    const int tid = threadIdx.x;
    const int c0 = blockIdx.x * VMC;
    const int b  = blockIdx.y;
    const int jg = blockIdx.z;
    const int ch = tid >> 2;
    const int r  = tid & 3;
    const int ts  = tid >> 5;
    const int k16 = (tid & 31) * 4;
    const float* gbase = X + ((size_t)ts * BATCH + b) * DIN + k16;
#define STAGE(cc, buf)                                                          \
    {                                                                           \
        const float* g0 = gbase + (size_t)(cc) * CHUNK * BATCH * DIN;           \
        float* l0p = &Xs[buf][0] + tid * 4;                                     \
        _Pragma("unroll")                                                       \
        for (int s = 0; s < 4; ++s)                                             \
            async_copy16(g0 + (size_t)s * 8 * BATCH * DIN, l0p + s * 1024);     \
    }
    STAGE(c0, 0)
    float wxr[VNCH][32];
    int jn[VNCH];
    float whn[VNCH], bh4[VNCH];
#pragma unroll
    for (int n = 0; n < VNCH; ++n) {
        jn[n] = jg * 256 + n * 64 + ch;
        whn[n] = wh[jn[n]];
        bh4[n] = bh[jn[n]] * 0.25f;
    }
#pragma unroll
    for (int s = 0; s < 4; ++s)
#pragma unroll
        for (int i = 0; i < 8; ++i) {
            const size_t krow = (size_t)(8 * r + 32 * s + i) * DLAT;
#pragma unroll
            for (int n = 0; n < VNCH; ++n)
                wxr[n][s * 8 + i] = wx[krow + jn[n]];
        }
    asm volatile("s_waitcnt vmcnt(0)" ::: "memory");
    __syncthreads();
    for (int m = 0; m < VMC; ++m) {
        const int c   = c0 + m;
        const int buf = m & 1;
        if (m + 1 < VMC)
            STAGE(c + 1, (m + 1) & 1)
        float l[VNCH] = {0.f, 0.f, 0.f, 0.f};
        for (int g = 0; g < 8; ++g) {
            float snap[VNCH] = {0.f, 0.f, 0.f, 0.f};
#pragma unroll
            for (int q = 0; q < 4; ++q) {
                const float* xt = &Xs[buf][0] + (g * 4 + q) * DIN + 8 * r;
                float acc[VNCH] = {bh4[0], bh4[1], bh4[2], bh4[3]};
#pragma unroll
                for (int s = 0; s < 4; ++s) {
                    const float4 xa = *(const float4*)(xt + 32 * s);
                    const float4 xc = *(const float4*)(xt + 32 * s + 4);
#pragma unroll
                    for (int n = 0; n < VNCH; ++n) {
                        acc[n] = fmaf(xa.x, wxr[n][s * 8 + 0], acc[n]);
                        acc[n] = fmaf(xa.y, wxr[n][s * 8 + 1], acc[n]);
                        acc[n] = fmaf(xa.z, wxr[n][s * 8 + 2], acc[n]);
                        acc[n] = fmaf(xa.w, wxr[n][s * 8 + 3], acc[n]);
                        acc[n] = fmaf(xc.x, wxr[n][s * 8 + 4], acc[n]);
                        acc[n] = fmaf(xc.y, wxr[n][s * 8 + 5], acc[n]);
                        acc[n] = fmaf(xc.z, wxr[n][s * 8 + 6], acc[n]);
                        acc[n] = fmaf(xc.w, wxr[n][s * 8 + 7], acc[n]);
                    }
                }
#pragma unroll
                for (int n = 0; n < VNCH; ++n) {
                    float a = dpp_add_xor1(acc[n]);
                    a = dpp_add_xor2(a);
                    l[n] = fmaf(l[n], whn[n], a);
                    snap[n] = (q == r) ? l[n] : snap[n];
                }
            }
            const int t = c * CHUNK + g * 4 + r;
            const size_t row = (size_t)t * (BATCH * DLAT) + (size_t)b * DLAT;
#pragma unroll
            for (int n = 0; n < VNCH; ++n)
                out[row + jn[n]] = snap[n];
        }
        if (r == 0) {
            const size_t fb = ((size_t)c * BATCH + b) * DLAT;
#pragma unroll
            for (int n = 0; n < VNCH; ++n)
                F[fb + jn[n]] = l[n];
        }
        asm volatile("s_waitcnt vmcnt(0)" ::: "memory");
        __syncthreads();
    }
#undef STAGE
}

// ---------------------------------------------------------------------------
// Kernel B0: sequential prefix -> Hpre[c]. grid (BATCH), block 128.
// ---------------------------------------------------------------------------
__global__ __launch_bounds__(128) void rnn_prefix(
    const float* __restrict__ h0, const float* __restrict__ wh,
    const float* __restrict__ F, float* __restrict__ Hpre)
{
    const int b  = blockIdx.x;
    const int j4 = threadIdx.x * 4;
    const size_t cb = (size_t)b * DLAT + j4;
    float4 w4 = *(const float4*)(wh + j4);
    float wv[4] = {w4.x, w4.y, w4.z, w4.w};
    float wc[4];
#pragma unroll
    for (int k = 0; k < 4; ++k) {
        float t = wv[k];
        t = t * t; t = t * t; t = t * t; t = t * t; t = t * t;
        wc[k] = t;
    }
    float4 h4 = *(const float4*)(h0 + cb);
    float Hv[4] = {h4.x, h4.y, h4.z, h4.w};
    for (int cg = 0; cg < NCHUNK / 4; ++cg) {
        float4 Fv[4];
#pragma unroll
        for (int i = 0; i < 4; ++i)
            Fv[i] = *(const float4*)(F + (size_t)(cg * 4 + i) * (BATCH * DLAT) + cb);
#pragma unroll
        for (int i = 0; i < 4; ++i) {
            float4 o = {Hv[0], Hv[1], Hv[2], Hv[3]};
            *(float4*)(Hpre + (size_t)(cg * 4 + i) * (BATCH * DLAT) + cb) = o;
            Hv[0] = fmaf(Hv[0], wc[0], Fv[i].x);
            Hv[1] = fmaf(Hv[1], wc[1], Fv[i].y);
            Hv[2] = fmaf(Hv[2], wc[2], Fv[i].z);
            Hv[3] = fmaf(Hv[3], wc[3], Fv[i].w);
        }
    }
}

// ---------------------------------------------------------------------------
// Kernel C: streaming fixup out_t = tanh(l_t + wh^{d+1} * Hpre[c]).
// ---------------------------------------------------------------------------
__global__ __launch_bounds__(256) void rnn_fix2(
    const float* __restrict__ wh, const float* __restrict__ Hpre,
    float* __restrict__ out)
{
    const int tid = threadIdx.x;
    const int c   = blockIdx.x * 2 + (tid >> 7);
    const int b   = blockIdx.y;
    const int j4  = (tid & 127) * 4;
    const size_t cb = (size_t)b * DLAT + j4;
    float4 w4 = *(const float4*)(wh + j4);
    float4 H4 = *(const float4*)(Hpre + (size_t)c * (BATCH * DLAT) + cb);
    float wv[4] = {w4.x, w4.y, w4.z, w4.w};
    float Hv[4] = {H4.x, H4.y, H4.z, H4.w};
    float sc[4] = {wv[0], wv[1], wv[2], wv[3]};
#pragma unroll 4
    for (int d = 0; d < CHUNK; ++d) {
        const size_t off = ((size_t)(c * CHUNK + d) * BATCH + b) * DLAT + j4;
        float4 l4 = *(const float4*)(out + off);
        float4 res;
        res.x = tanhf(fmaf(sc[0], Hv[0], l4.x));
        res.y = tanhf(fmaf(sc[1], Hv[1], l4.y));
        res.z = tanhf(fmaf(sc[2], Hv[2], l4.z));
        res.w = tanhf(fmaf(sc[3], Hv[3], l4.w));
        *(float4*)(out + off) = res;
        sc[0] *= wv[0]; sc[1] *= wv[1]; sc[2] *= wv[2]; sc[3] *= wv[3];
    }
}

// Fallback fixup: fold H per block from F.
__global__ __launch_bounds__(256) void rnn_fix(
    const float* __restrict__ h0, const float* __restrict__ wh,
    const float* __restrict__ F, float* __restrict__ out)
{
    const int tid = threadIdx.x;
    const int c   = blockIdx.x * 2 + (tid >> 7);
    const int b   = blockIdx.y;
    const int j4  = (tid & 127) * 4;
    const size_t cb = (size_t)b * DLAT + j4;
    float4 h4 = *(const float4*)(h0 + cb);
    float4 w4 = *(const float4*)(wh + j4);
    float Hv[4] = {h4.x, h4.y, h4.z, h4.w};
    float wv[4] = {w4.x, w4.y, w4.z, w4.w};
    float wc[4];
#pragma unroll
    for (int k = 0; k < 4; ++k) {
        float t = wv[k];
        t = t * t; t = t * t; t = t * t; t = t * t; t = t * t;
        wc[k] = t;
    }
    for (int cc = 0; cc < c; ++cc) {
        const float4 Fv = *(const float4*)(F + ((size_t)cc * BATCH + b) * DLAT + j4);
        Hv[0] = fmaf(Hv[0], wc[0], Fv.x);
        Hv[1] = fmaf(Hv[1], wc[1], Fv.y);
        Hv[2] = fmaf(Hv[2], wc[2], Fv.z);
        Hv[3] = fmaf(Hv[3], wc[3], Fv.w);
    }
    float sc[4] = {wv[0], wv[1], wv[2], wv[3]};
    for (int d = 0; d < CHUNK; ++d) {
        const size_t off = ((size_t)(c * CHUNK + d) * BATCH + b) * DLAT + j4;
        float4 l4 = *(const float4*)(out + off);
        float4 res;
        res.x = tanhf(fmaf(sc[0], Hv[0], l4.x));
        res.y = tanhf(fmaf(sc[1], Hv[1], l4.y));
        res.z = tanhf(fmaf(sc[2], Hv[2], l4.z));
        res.w = tanhf(fmaf(sc[3], Hv[3], l4.w));
        *(float4*)(out + off) = res;
        sc[0] *= wv[0]; sc[1] *= wv[1]; sc[2] *= wv[2]; sc[3] *= wv[3];
    }
}

extern "C" void kernel_launch(void* const* d_in, const int* in_sizes, int n_in,
                              void* d_out, int out_size, void* d_ws, size_t ws_size,
                              hipStream_t stream) {
    const float* X  = (const float*)d_in[0];
    const float* h0 = (const float*)d_in[1];
    const float* wx = (const float*)d_in[2];
    const float* wh = (const float*)d_in[3];
    const float* bh = (const float*)d_in[4];
    float* out = (float*)d_out;

    const size_t seg = (size_t)NCHUNK * BATCH * DLAT;   // 2M floats = 8 MiB
    const size_t wxt_elems = 4 * 32 * 64 * 8;           // 65536 ushorts = 128 KB
    float* F = (float*)d_ws;
    unsigned short* wxtH = (unsigned short*)(F + seg);
    unsigned short* wxtM = wxtH + wxt_elems;
    unsigned short* wxtL = wxtM + wxt_elems;
    float* Hpre = (float*)(wxtL + wxt_elems);

    const size_t need_mid  = seg * 4 + wxt_elems * 3 * 2;   // F + wxt  = 8.375 MiB
    const size_t need_full = need_mid + seg * 4;            // + Hpre   = 16.375 MiB

    if (ws_size >= need_mid) {
        wx_transform<<<dim3(32), dim3(256), 0, stream>>>(wx, wxtH, wxtM, wxtL);
        rnn_local_mfma<<<dim3(NCHUNK, BATCH), dim3(256), 0, stream>>>(
            X, wxtH, wxtM, wxtL, wh, bh, out, F);
        if (ws_size >= need_full) {
            rnn_prefix<<<dim3(BATCH), dim3(128), 0, stream>>>(h0, wh, F, Hpre);
            rnn_fix2<<<dim3(NCHUNK / 2, BATCH), dim3(256), 0, stream>>>(wh, Hpre, out);
        } else {
            rnn_fix<<<dim3(NCHUNK / 2, BATCH), dim3(256), 0, stream>>>(h0, wh, F, out);
        }
    } else {
        rnn_local_valu<<<dim3(NCHUNK / VMC, BATCH, 2), dim3(256), 0, stream>>>(
            X, wx, wh, bh, out, F);
        rnn_fix<<<dim3(NCHUNK / 2, BATCH), dim3(256), 0, stream>>>(h0, wh, F, out);
    }
}

// Round 14
// 231.129 us; speedup vs baseline: 3.3281x; 1.0305x over previous
//
#include <hip/hip_runtime.h>
#include <cstdint>
#include <cstddef>

#define L_SEQ 4096
#define BATCH 32
#define DIN 128
#define DLAT 512
#define CHUNK 32
#define NCHUNK (L_SEQ / CHUNK)   // 128
#define USTRIDE 522              // (4*522)%32==8 -> row-groups on banks {0,8,16,24}: 2-way max

typedef __attribute__((ext_vector_type(8))) short short8;
typedef __attribute__((ext_vector_type(4))) float f32x4;

// 3-way Dekker-style split: x = h + m + l + r, |r| <= 2^-27 |x|.
__device__ __forceinline__ unsigned short bf16rne(float x) {
    unsigned int b = __builtin_bit_cast(unsigned int, x);
    unsigned int r = b + 0x7FFFu + ((b >> 16) & 1u);
    return (unsigned short)(r >> 16);
}
__device__ __forceinline__ float bf16tof(unsigned short h) {
    return __builtin_bit_cast(float, (unsigned int)h << 16);
}
__device__ __forceinline__ void bf16split3(float x, unsigned short& h,
                                           unsigned short& m, unsigned short& l) {
    h = bf16rne(x);
    float r1 = x - bf16tof(h);
    m = bf16rne(r1);
    float r2 = r1 - bf16tof(m);
    l = bf16rne(r2);
}

__device__ __forceinline__ void async_copy16(const float* g, float* l) {
    __builtin_amdgcn_global_load_lds(
        (const __attribute__((address_space(1))) unsigned int*)g,
        (__attribute__((address_space(3))) unsigned int*)l,
        16, 0, 0);
}
__device__ __forceinline__ float dpp_add_xor1(float x) {
    int r = __builtin_amdgcn_update_dpp(0, __builtin_bit_cast(int, x),
                                        0xB1, 0xF, 0xF, true);
    return x + __builtin_bit_cast(float, r);
}
__device__ __forceinline__ float dpp_add_xor2(float x) {
    int r = __builtin_amdgcn_update_dpp(0, __builtin_bit_cast(int, x),
                                        0x4E, 0xF, 0xF, true);
    return x + __builtin_bit_cast(float, r);
}

// ---------------------------------------------------------------------------
// Kernel W: one-time transform of wx [128][512] fp32 into MFMA B-fragment
// layout, bf16 h/m/l. Frag fid = kt*32 + nt; lane holds col n = nt*16+(lane&15),
// k = kt*32 + (lane>>4)*8 + i. 3 x 128 KB into ws.
// ---------------------------------------------------------------------------
__global__ __launch_bounds__(256) void wx_transform(
    const float* __restrict__ wx,
    unsigned short* __restrict__ wxtH,
    unsigned short* __restrict__ wxtM,
    unsigned short* __restrict__ wxtL)
{
    const int gid  = blockIdx.x * 256 + threadIdx.x;  // 8192 threads
    const int fid  = gid >> 6;        // 0..127
    const int lane = gid & 63;
    const int kt = fid >> 5, nt = fid & 31;
    const int n  = nt * 16 + (lane & 15);
    const int kb = kt * 32 + (lane >> 4) * 8;

    short8 h8, m8, l8;
#pragma unroll
    for (int i = 0; i < 8; ++i) {
        unsigned short h, m, l;
        bf16split3(wx[(size_t)(kb + i) * DLAT + n], h, m, l);
        h8[i] = (short)h; m8[i] = (short)m; l8[i] = (short)l;
    }
    ((short8*)wxtH)[fid * 64 + lane] = h8;
    ((short8*)wxtM)[fid * 64 + lane] = m8;
    ((short8*)wxtL)[fid * 64 + lane] = l8;
}

// ---------------------------------------------------------------------------
// Kernel A (MFMA): per block = chunk c x batch b x ALL 512 channels.
// LDS: AF (24 KB, A-fragments) and U (33.4 KB, GEMM output tile) UNIONED --
// AF dies at end of Phase M, U born after -> one 33.4 KB buffer, 4 blocks/CU
// (was 57.9 KB -> 2 blocks/CU, occupancy 21.6%).
// Phase S: X chunk -> regs -> bf16 h/m/l -> AF.
// Phase M: 6-product emulation (mm,lh,hl,mh,hm,hh smallest-first), 384 MFMA/wave.
// Phase U/scan per m-tile: acc -> U[16][USTRIDE] -> serial scan (2 ch/thread).
// grid (NCHUNK, BATCH) = 4096 blocks, 256 threads.
// ---------------------------------------------------------------------------
__global__ __launch_bounds__(256) void rnn_local_mfma(
    const float* __restrict__ X,          // [L, B, DIN]
    const unsigned short* __restrict__ wxtH,
    const unsigned short* __restrict__ wxtM,
    const unsigned short* __restrict__ wxtL,
    const float* __restrict__ wh,         // [DLAT]
    const float* __restrict__ bh,         // [DLAT]
    float* __restrict__ out,              // [L, B, DLAT] pre-tanh locals
    float* __restrict__ F)                // [NCHUNK, B, DLAT]
{
    // Union: AF needs 24*512*2 = 24576 B; U needs 16*USTRIDE*4 = 33408 B.
    __shared__ __align__(16) char smem[16 * USTRIDE * 4];
    unsigned short* AF = (unsigned short*)smem;
    float* U = (float*)smem;

    const int tid  = threadIdx.x;
    const int c = blockIdx.x, b = blockIdx.y;
    const int w = tid >> 6, lane = tid & 63;

    // ---- Phase S: stage + 3-way convert. 2 frag-slots per thread. ----
#pragma unroll
    for (int sl = 0; sl < 2; ++sl) {
        const int slot = tid + sl * 256;
        const int f  = slot >> 6;        // m*4 + kt  (0..7)
        const int ls = slot & 63;
        const int m  = f >> 2, kt = f & 3;
        const int t  = c * CHUNK + m * 16 + (ls & 15);
        const int kb = kt * 32 + (ls >> 4) * 8;
        const float* p = X + ((size_t)t * BATCH + b) * DIN + kb;
        const float4 va = *(const float4*)p;
        const float4 vb = *(const float4*)(p + 4);
        float v[8] = {va.x, va.y, va.z, va.w, vb.x, vb.y, vb.z, vb.w};
        short8 h8, m8, l8;
#pragma unroll
        for (int i = 0; i < 8; ++i) {
            unsigned short h, mm, l;
            bf16split3(v[i], h, mm, l);
            h8[i] = (short)h; m8[i] = (short)mm; l8[i] = (short)l;
        }
        ((short8*)AF)[(f * 3 + 0) * 64 + ls] = h8;
        ((short8*)AF)[(f * 3 + 1) * 64 + ls] = m8;
        ((short8*)AF)[(f * 3 + 2) * 64 + ls] = l8;
    }
    __syncthreads();

    // ---- Phase M: MFMA. Wave w owns channels [w*128, w*128+128). ----
    f32x4 acc[2][8];
#pragma unroll
    for (int m = 0; m < 2; ++m)
#pragma unroll
        for (int j = 0; j < 8; ++j)
            acc[m][j] = (f32x4){0.f, 0.f, 0.f, 0.f};

    const short8* AFv = (const short8*)AF;
    const short8* BH  = (const short8*)wxtH;
    const short8* BM  = (const short8*)wxtM;
    const short8* BL  = (const short8*)wxtL;

#pragma unroll
    for (int kt = 0; kt < 4; ++kt) {
        const short8 a0h = AFv[((0 * 4 + kt) * 3 + 0) * 64 + lane];
        const short8 a0m = AFv[((0 * 4 + kt) * 3 + 1) * 64 + lane];
        const short8 a0l = AFv[((0 * 4 + kt) * 3 + 2) * 64 + lane];
        const short8 a1h = AFv[((1 * 4 + kt) * 3 + 0) * 64 + lane];
        const short8 a1m = AFv[((1 * 4 + kt) * 3 + 1) * 64 + lane];
        const short8 a1l = AFv[((1 * 4 + kt) * 3 + 2) * 64 + lane];
#pragma unroll
        for (int j = 0; j < 8; ++j) {
            const int idx = (kt * 32 + w * 8 + j) * 64 + lane;
            const short8 bh8 = BH[idx];
            const short8 bm8 = BM[idx];
            const short8 bl8 = BL[idx];
            // smallest-first: mm, al*bh, ah*bl, am*bh, ah*bm, ah*bh
            acc[0][j] = __builtin_amdgcn_mfma_f32_16x16x32_bf16(a0m, bm8, acc[0][j], 0, 0, 0);
            acc[0][j] = __builtin_amdgcn_mfma_f32_16x16x32_bf16(a0l, bh8, acc[0][j], 0, 0, 0);
            acc[0][j] = __builtin_amdgcn_mfma_f32_16x16x32_bf16(a0h, bl8, acc[0][j], 0, 0, 0);
            acc[0][j] = __builtin_amdgcn_mfma_f32_16x16x32_bf16(a0m, bh8, acc[0][j], 0, 0, 0);
            acc[0][j] = __builtin_amdgcn_mfma_f32_16x16x32_bf16(a0h, bm8, acc[0][j], 0, 0, 0);
            acc[0][j] = __builtin_amdgcn_mfma_f32_16x16x32_bf16(a0h, bh8, acc[0][j], 0, 0, 0);
            acc[1][j] = __builtin_amdgcn_mfma_f32_16x16x32_bf16(a1m, bm8, acc[1][j], 0, 0, 0);
            acc[1][j] = __builtin_amdgcn_mfma_f32_16x16x32_bf16(a1l, bh8, acc[1][j], 0, 0, 0);
            acc[1][j] = __builtin_amdgcn_mfma_f32_16x16x32_bf16(a1h, bl8, acc[1][j], 0, 0, 0);
            acc[1][j] = __builtin_amdgcn_mfma_f32_16x16x32_bf16(a1m, bh8, acc[1][j], 0, 0, 0);
            acc[1][j] = __builtin_amdgcn_mfma_f32_16x16x32_bf16(a1h, bm8, acc[1][j], 0, 0, 0);
            acc[1][j] = __builtin_amdgcn_mfma_f32_16x16x32_bf16(a1h, bh8, acc[1][j], 0, 0, 0);
        }
    }

    // ---- Phase U/scan: two m-tiles through the unioned U buffer. ----
    const int ch = tid * 2;                           // 2 channels per thread
    const float2 whv = *(const float2*)(wh + ch);
    const float2 bhv = *(const float2*)(bh + ch);
    float l0 = 0.f, l1 = 0.f;

#pragma unroll
    for (int m = 0; m < 2; ++m) {
        __syncthreads();   // m=0: all AF reads done (union!); m=1: scan0 reads done
        // D layout (m89-verified): col = lane&15, row = (lane>>4)*4 + reg.
#pragma unroll
        for (int j = 0; j < 8; ++j) {
            const int col = w * 128 + j * 16 + (lane & 15);
#pragma unroll
            for (int r4 = 0; r4 < 4; ++r4)
                U[((lane >> 4) * 4 + r4) * USTRIDE + col] = acc[m][j][r4];
        }
        __syncthreads();
        for (int tl = 0; tl < 16; ++tl) {
            const float2 u = *(const float2*)&U[tl * USTRIDE + ch];
            l0 = fmaf(l0, whv.x, u.x + bhv.x);
            l1 = fmaf(l1, whv.y, u.y + bhv.y);
            const int t = c * CHUNK + m * 16 + tl;
            float2 o; o.x = l0; o.y = l1;
            *(float2*)(out + ((size_t)t * BATCH + b) * DLAT + ch) = o;
        }
    }

    float2 fo; fo.x = l0; fo.y = l1;
    *(float2*)(F + ((size_t)c * BATCH + b) * DLAT + ch) = fo;
}

// ---------------------------------------------------------------------------
// VALU fallback kernel A (proven R8 config) — used only if ws too small.
// ---------------------------------------------------------------------------
#define VMC 4
#define VNCH 4
__global__ __launch_bounds__(256, 2) void rnn_local_valu(
    const float* __restrict__ X, const float* __restrict__ wx,
    const float* __restrict__ wh, const float* __restrict__ bh,
    float* __restrict__ out, float* __restrict__ F)
{
    __shared__ float Xs[2][CHUNK * DIN];
    const int tid = threadIdx.x;
    const int c0 = blockIdx.x * VMC;
    const int b  = blockIdx.y;
    const int jg = blockIdx.z;
    const int ch = tid >> 2;
    const int r  = tid & 3;
    const int ts  = tid >> 5;
    const int k16 = (tid & 31) * 4;
    const float* gbase = X + ((size_t)ts * BATCH + b) * DIN + k16;
#define STAGE(cc, buf)                                                          \
    {                                                                           \
        const float* g0 = gbase + (size_t)(cc) * CHUNK * BATCH * DIN;           \
        float* l0p = &Xs[buf][0] + tid * 4;                                     \
        _Pragma("unroll")                                                       \
        for (int s = 0; s < 4; ++s)                                             \
            async_copy16(g0 + (size_t)s * 8 * BATCH * DIN, l0p + s * 1024);     \
    }
    STAGE(c0, 0)
    float wxr[VNCH][32];
    int jn[VNCH];
    float whn[VNCH], bh4[VNCH];
#pragma unroll
    for (int n = 0; n < VNCH; ++n) {
        jn[n] = jg * 256 + n * 64 + ch;
        whn[n] = wh[jn[n]];
        bh4[n] = bh[jn[n]] * 0.25f;
    }
#pragma unroll
    for (int s = 0; s < 4; ++s)
#pragma unroll
        for (int i = 0; i < 8; ++i) {
            const size_t krow = (size_t)(8 * r + 32 * s + i) * DLAT;
#pragma unroll
            for (int n = 0; n < VNCH; ++n)
                wxr[n][s * 8 + i] = wx[krow + jn[n]];
        }
    asm volatile("s_waitcnt vmcnt(0)" ::: "memory");
    __syncthreads();
    for (int m = 0; m < VMC; ++m) {
        const int c   = c0 + m;
        const int buf = m & 1;
        if (m + 1 < VMC)
            STAGE(c + 1, (m + 1) & 1)
        float l[VNCH] = {0.f, 0.f, 0.f, 0.f};
        for (int g = 0; g < 8; ++g) {
            float snap[VNCH] = {0.f, 0.f, 0.f, 0.f};
#pragma unroll
            for (int q = 0; q < 4; ++q) {
                const float* xt = &Xs[buf][0] + (g * 4 + q) * DIN + 8 * r;
                float acc[VNCH] = {bh4[0], bh4[1], bh4[2], bh4[3]};
#pragma unroll
                for (int s = 0; s < 4; ++s) {
                    const float4 xa = *(const float4*)(xt + 32 * s);
                    const float4 xc = *(const float4*)(xt + 32 * s + 4);
#pragma unroll
                    for (int n = 0; n < VNCH; ++n) {
                        acc[n] = fmaf(xa.x, wxr[n][s * 8 + 0], acc[n]);
                        acc[n] = fmaf(xa.y, wxr[n][s * 8 + 1], acc[n]);
                        acc[n] = fmaf(xa.z, wxr[n][s * 8 + 2], acc[n]);
                        acc[n] = fmaf(xa.w, wxr[n][s * 8 + 3], acc[n]);
                        acc[n] = fmaf(xc.x, wxr[n][s * 8 + 4], acc[n]);
                        acc[n] = fmaf(xc.y, wxr[n][s * 8 + 5], acc[n]);
                        acc[n] = fmaf(xc.z, wxr[n][s * 8 + 6], acc[n]);
                        acc[n] = fmaf(xc.w, wxr[n][s * 8 + 7], acc[n]);
                    }
                }
#pragma unroll
                for (int n = 0; n < VNCH; ++n) {
                    float a = dpp_add_xor1(acc[n]);
                    a = dpp_add_xor2(a);
                    l[n] = fmaf(l[n], whn[n], a);
                    snap[n] = (q == r) ? l[n] : snap[n];
                }
            }
            const int t = c * CHUNK + g * 4 + r;
            const size_t row = (size_t)t * (BATCH * DLAT) + (size_t)b * DLAT;
#pragma unroll
            for (int n = 0; n < VNCH; ++n)
                out[row + jn[n]] = snap[n];
        }
        if (r == 0) {
            const size_t fb = ((size_t)c * BATCH + b) * DLAT;
#pragma unroll
            for (int n = 0; n < VNCH; ++n)
                F[fb + jn[n]] = l[n];
        }
        asm volatile("s_waitcnt vmcnt(0)" ::: "memory");
        __syncthreads();
    }
#undef STAGE
}

// ---------------------------------------------------------------------------
// Kernel B0: sequential prefix -> Hpre[c]. grid (BATCH), block 128.
// ---------------------------------------------------------------------------
__global__ __launch_bounds__(128) void rnn_prefix(
    const float* __restrict__ h0, const float* __restrict__ wh,
    const float* __restrict__ F, float* __restrict__ Hpre)
{
    const int b  = blockIdx.x;
    const int j4 = threadIdx.x * 4;
    const size_t cb = (size_t)b * DLAT + j4;
    float4 w4 = *(const float4*)(wh + j4);
    float wv[4] = {w4.x, w4.y, w4.z, w4.w};
    float wc[4];
#pragma unroll
    for (int k = 0; k < 4; ++k) {
        float t = wv[k];
        t = t * t; t = t * t; t = t * t; t = t * t; t = t * t;
        wc[k] = t;
    }
    float4 h4 = *(const float4*)(h0 + cb);
    float Hv[4] = {h4.x, h4.y, h4.z, h4.w};
    for (int cg = 0; cg < NCHUNK / 4; ++cg) {
        float4 Fv[4];
#pragma unroll
        for (int i = 0; i < 4; ++i)
            Fv[i] = *(const float4*)(F + (size_t)(cg * 4 + i) * (BATCH * DLAT) + cb);
#pragma unroll
        for (int i = 0; i < 4; ++i) {
            float4 o = {Hv[0], Hv[1], Hv[2], Hv[3]};
            *(float4*)(Hpre + (size_t)(cg * 4 + i) * (BATCH * DLAT) + cb) = o;
            Hv[0] = fmaf(Hv[0], wc[0], Fv[i].x);
            Hv[1] = fmaf(Hv[1], wc[1], Fv[i].y);
            Hv[2] = fmaf(Hv[2], wc[2], Fv[i].z);
            Hv[3] = fmaf(Hv[3], wc[3], Fv[i].w);
        }
    }
}

// ---------------------------------------------------------------------------
// Kernel C: streaming fixup out_t = tanh(l_t + wh^{d+1} * Hpre[c]).
// ---------------------------------------------------------------------------
__global__ __launch_bounds__(256) void rnn_fix2(
    const float* __restrict__ wh, const float* __restrict__ Hpre,
    float* __restrict__ out)
{
    const int tid = threadIdx.x;
    const int c   = blockIdx.x * 2 + (tid >> 7);
    const int b   = blockIdx.y;
    const int j4  = (tid & 127) * 4;
    const size_t cb = (size_t)b * DLAT + j4;
    float4 w4 = *(const float4*)(wh + j4);
    float4 H4 = *(const float4*)(Hpre + (size_t)c * (BATCH * DLAT) + cb);
    float wv[4] = {w4.x, w4.y, w4.z, w4.w};
    float Hv[4] = {H4.x, H4.y, H4.z, H4.w};
    float sc[4] = {wv[0], wv[1], wv[2], wv[3]};
#pragma unroll 4
    for (int d = 0; d < CHUNK; ++d) {
        const size_t off = ((size_t)(c * CHUNK + d) * BATCH + b) * DLAT + j4;
        float4 l4 = *(const float4*)(out + off);
        float4 res;
        res.x = tanhf(fmaf(sc[0], Hv[0], l4.x));
        res.y = tanhf(fmaf(sc[1], Hv[1], l4.y));
        res.z = tanhf(fmaf(sc[2], Hv[2], l4.z));
        res.w = tanhf(fmaf(sc[3], Hv[3], l4.w));
        *(float4*)(out + off) = res;
        sc[0] *= wv[0]; sc[1] *= wv[1]; sc[2] *= wv[2]; sc[3] *= wv[3];
    }
}

// Fallback fixup: fold H per block from F.
__global__ __launch_bounds__(256) void rnn_fix(
    const float* __restrict__ h0, const float* __restrict__ wh,
    const float* __restrict__ F, float* __restrict__ out)
{
    const int tid = threadIdx.x;
    const int c   = blockIdx.x * 2 + (tid >> 7);
    const int b   = blockIdx.y;
    const int j4  = (tid & 127) * 4;
    const size_t cb = (size_t)b * DLAT + j4;
    float4 h4 = *(const float4*)(h0 + cb);
    float4 w4 = *(const float4*)(wh + j4);
    float Hv[4] = {h4.x, h4.y, h4.z, h4.w};
    float wv[4] = {w4.x, w4.y, w4.z, w4.w};
    float wc[4];
#pragma unroll
    for (int k = 0; k < 4; ++k) {
        float t = wv[k];
        t = t * t; t = t * t; t = t * t; t = t * t; t = t * t;
        wc[k] = t;
    }
    for (int cc = 0; cc < c; ++cc) {
        const float4 Fv = *(const float4*)(F + ((size_t)cc * BATCH + b) * DLAT + j4);
        Hv[0] = fmaf(Hv[0], wc[0], Fv.x);
        Hv[1] = fmaf(Hv[1], wc[1], Fv.y);
        Hv[2] = fmaf(Hv[2], wc[2], Fv.z);
        Hv[3] = fmaf(Hv[3], wc[3], Fv.w);
    }
    float sc[4] = {wv[0], wv[1], wv[2], wv[3]};
    for (int d = 0; d < CHUNK; ++d) {
        const size_t off = ((size_t)(c * CHUNK + d) * BATCH + b) * DLAT + j4;
        float4 l4 = *(const float4*)(out + off);
        float4 res;
        res.x = tanhf(fmaf(sc[0], Hv[0], l4.x));
        res.y = tanhf(fmaf(sc[1], Hv[1], l4.y));
        res.z = tanhf(fmaf(sc[2], Hv[2], l4.z));
        res.w = tanhf(fmaf(sc[3], Hv[3], l4.w));
        *(float4*)(out + off) = res;
        sc[0] *= wv[0]; sc[1] *= wv[1]; sc[2] *= wv[2]; sc[3] *= wv[3];
    }
}

extern "C" void kernel_launch(void* const* d_in, const int* in_sizes, int n_in,
                              void* d_out, int out_size, void* d_ws, size_t ws_size,
                              hipStream_t stream) {
    const float* X  = (const float*)d_in[0];
    const float* h0 = (const float*)d_in[1];
    const float* wx = (const float*)d_in[2];
    const float* wh = (const float*)d_in[3];
    const float* bh = (const float*)d_in[4];
    float* out = (float*)d_out;

    const size_t seg = (size_t)NCHUNK * BATCH * DLAT;   // 2M floats = 8 MiB
    const size_t wxt_elems = 4 * 32 * 64 * 8;           // 65536 ushorts = 128 KB
    float* F = (float*)d_ws;
    unsigned short* wxtH = (unsigned short*)(F + seg);
    unsigned short* wxtM = wxtH + wxt_elems;
    unsigned short* wxtL = wxtM + wxt_elems;
    float* Hpre = (float*)(wxtL + wxt_elems);

    const size_t need_mid  = seg * 4 + wxt_elems * 3 * 2;   // F + wxt  = 8.375 MiB
    const size_t need_full = need_mid + seg * 4;            // + Hpre   = 16.375 MiB

    if (ws_size >= need_mid) {
        wx_transform<<<dim3(32), dim3(256), 0, stream>>>(wx, wxtH, wxtM, wxtL);
        rnn_local_mfma<<<dim3(NCHUNK, BATCH), dim3(256), 0, stream>>>(
            X, wxtH, wxtM, wxtL, wh, bh, out, F);
        if (ws_size >= need_full) {
            rnn_prefix<<<dim3(BATCH), dim3(128), 0, stream>>>(h0, wh, F, Hpre);
            rnn_fix2<<<dim3(NCHUNK / 2, BATCH), dim3(256), 0, stream>>>(wh, Hpre, out);
        } else {
            rnn_fix<<<dim3(NCHUNK / 2, BATCH), dim3(256), 0, stream>>>(h0, wh, F, out);
        }
    } else {
        rnn_local_valu<<<dim3(NCHUNK / VMC, BATCH, 2), dim3(256), 0, stream>>>(
            X, wx, wh, bh, out, F);
        rnn_fix<<<dim3(NCHUNK / 2, BATCH), dim3(256), 0, stream>>>(h0, wh, F, out);
    }
}